// Round 1
// baseline (1551.898 us; speedup 1.0000x reference)
//
#include <hip/hip_runtime.h>
#include <hip/hip_bf16.h>

#define B_ 4
#define L_ 1024
#define D_ 1024
#define H_ 16
#define NROWS_ (B_ * L_)   // 4096

// ---------------- LayerNorm row stats (mean, rstd) for q,k,v ----------------
__global__ __launch_bounds__(256) void ln_stats_kernel(
    const float* __restrict__ q, const float* __restrict__ k, const float* __restrict__ v,
    float* __restrict__ stats)   // [3][NROWS_][2]
{
    const int row = blockIdx.x;
    const int which = blockIdx.y;
    const float* x = (which == 0 ? q : (which == 1 ? k : v)) + (size_t)row * D_;
    const int tid = threadIdx.x;
    float4 t4 = ((const float4*)x)[tid];            // 256 threads * 4 = 1024
    float s  = t4.x + t4.y + t4.z + t4.w;
    float s2 = t4.x*t4.x + t4.y*t4.y + t4.z*t4.z + t4.w*t4.w;
    #pragma unroll
    for (int off = 1; off < 64; off <<= 1) {
        s  += __shfl_xor(s,  off, 64);
        s2 += __shfl_xor(s2, off, 64);
    }
    __shared__ float red[8];
    const int wid = tid >> 6;
    if ((tid & 63) == 0) { red[wid*2] = s; red[wid*2+1] = s2; }
    __syncthreads();
    if (tid == 0) {
        s  = red[0] + red[2] + red[4] + red[6];
        s2 = red[1] + red[3] + red[5] + red[7];
        const float mean = s * (1.0f/(float)D_);
        const float var  = s2 * (1.0f/(float)D_) - mean*mean;
        float* st = stats + ((size_t)which * NROWS_ + row) * 2;
        st[0] = mean;
        st[1] = rsqrtf(var + 1e-5f);
    }
}

// ---------------- C[M,N] = LN(A)[M,K] @ W[N,K]^T  (NT GEMM, fp32) ----------------
// 128x128 block tile, BK=8, 256 threads, 8x8 micro-tile per thread.
__global__ __launch_bounds__(256) void gemm_nt_kernel(
    const float* __restrict__ A, const float* __restrict__ W,
    const float* __restrict__ stats, const float* __restrict__ lnw, const float* __restrict__ lnb,
    float* __restrict__ C, int M, int N, int K, int useLN)
{
    __shared__ float As[8][132];
    __shared__ float Bs[8][132];
    const int tid = threadIdx.x;
    const int bm = blockIdx.x * 128;
    const int bn = blockIdx.y * 128;
    const int lr  = tid >> 1;          // 0..127
    const int lk4 = (tid & 1) * 4;     // 0 or 4
    const float* Arow = A + (size_t)(bm + lr) * K + lk4;
    const float* Wrow = W + (size_t)(bn + lr) * K + lk4;
    float mu = 0.f, rstd = 0.f;
    if (useLN) {
        mu   = stats[(size_t)(bm + lr) * 2 + 0];
        rstd = stats[(size_t)(bm + lr) * 2 + 1];
    }
    const int ty = tid >> 4, tx = tid & 15;
    float acc[8][8] = {};
    for (int k0 = 0; k0 < K; k0 += 8) {
        float4 a = *(const float4*)(Arow + k0);
        if (useLN) {
            const float4 w4 = *(const float4*)(lnw + k0 + lk4);
            const float4 b4 = *(const float4*)(lnb + k0 + lk4);
            a.x = (a.x - mu) * rstd * w4.x + b4.x;
            a.y = (a.y - mu) * rstd * w4.y + b4.y;
            a.z = (a.z - mu) * rstd * w4.z + b4.z;
            a.w = (a.w - mu) * rstd * w4.w + b4.w;
        }
        const float4 b = *(const float4*)(Wrow + k0);
        As[lk4+0][lr] = a.x; As[lk4+1][lr] = a.y; As[lk4+2][lr] = a.z; As[lk4+3][lr] = a.w;
        Bs[lk4+0][lr] = b.x; Bs[lk4+1][lr] = b.y; Bs[lk4+2][lr] = b.z; Bs[lk4+3][lr] = b.w;
        __syncthreads();
        #pragma unroll
        for (int kk = 0; kk < 8; kk++) {
            float av[8], bv[8];
            *(float4*)&av[0] = *(const float4*)&As[kk][ty*8];
            *(float4*)&av[4] = *(const float4*)&As[kk][ty*8+4];
            *(float4*)&bv[0] = *(const float4*)&Bs[kk][tx*8];
            *(float4*)&bv[4] = *(const float4*)&Bs[kk][tx*8+4];
            #pragma unroll
            for (int i = 0; i < 8; i++)
                #pragma unroll
                for (int j = 0; j < 8; j++)
                    acc[i][j] += av[i] * bv[j];
        }
        __syncthreads();
    }
    for (int i = 0; i < 8; i++) {
        float* Crow = C + (size_t)(bm + ty*8 + i) * N + (bn + tx*8);
        *(float4*)(Crow + 0) = make_float4(acc[i][0], acc[i][1], acc[i][2], acc[i][3]);
        *(float4*)(Crow + 4) = make_float4(acc[i][4], acc[i][5], acc[i][6], acc[i][7]);
    }
}

// ---------------- attention: S = mask? -1e32 : QK^T/8 ; softmax; write p; ctx = pV ----
// One block = 8 query rows of one (b,h). 256 threads.
__global__ __launch_bounds__(256) void attn_kernel(
    const float* __restrict__ qh, const float* __restrict__ kh, const float* __restrict__ vh,
    const int* __restrict__ mask, float* __restrict__ attn_out, float* __restrict__ ctx)
{
    __shared__ float S[8][1028];     // padded: stride 1028 floats (16B-aligned rows)
    __shared__ float Qs[8][68];
    __shared__ float KVs[64][68];
    __shared__ float invs[8];
    const int t = threadIdx.x;
    const int q0 = blockIdx.x * 8;
    const int h = blockIdx.y;
    const int b = blockIdx.z;

    // Q tile, prescaled by 1/sqrt(DK)=0.125
    if (t < 128) {
        const int row = t >> 4, d4 = (t & 15) * 4;
        float4 qv = *(const float4*)(qh + (size_t)(b*L_ + q0 + row) * D_ + h*64 + d4);
        qv.x *= 0.125f; qv.y *= 0.125f; qv.z *= 0.125f; qv.w *= 0.125f;
        *(float4*)&Qs[row][d4] = qv;
    }
    __syncthreads();

    const int r  = t >> 5;   // 0..7
    const int cx = t & 31;   // 0..31

    // ---- S phase ----
    for (int k0 = 0; k0 < L_; k0 += 64) {
        {
            const int kk = t >> 2, db = (t & 3) * 16;
            const float* src = kh + (size_t)(b*L_ + k0 + kk) * D_ + h*64 + db;
            float4 v0 = *(const float4*)(src + 0);
            float4 v1 = *(const float4*)(src + 4);
            float4 v2 = *(const float4*)(src + 8);
            float4 v3 = *(const float4*)(src + 12);
            *(float4*)&KVs[kk][db +  0] = v0;
            *(float4*)&KVs[kk][db +  4] = v1;
            *(float4*)&KVs[kk][db +  8] = v2;
            *(float4*)&KVs[kk][db + 12] = v3;
        }
        __syncthreads();
        const int cb = cx * 2;
        float a0 = 0.f, a1 = 0.f;
        #pragma unroll
        for (int d4 = 0; d4 < 64; d4 += 4) {
            const float4 qv  = *(const float4*)&Qs[r][d4];
            const float4 k0v = *(const float4*)&KVs[cb+0][d4];
            const float4 k1v = *(const float4*)&KVs[cb+1][d4];
            a0 += qv.x*k0v.x + qv.y*k0v.y + qv.z*k0v.z + qv.w*k0v.w;
            a1 += qv.x*k1v.x + qv.y*k1v.y + qv.z*k1v.z + qv.w*k1v.w;
        }
        const int2 mv = *(const int2*)(mask + (size_t)(b*L_ + q0 + r) * L_ + k0 + cb);
        S[r][k0+cb+0] = mv.x ? -1e32f : a0;
        S[r][k0+cb+1] = mv.y ? -1e32f : a1;
        __syncthreads();
    }

    // ---- row softmax (32 lanes per row; masked entries -> exactly 0) ----
    {
        float mx = -3.0e38f;
        for (int i = cx; i < L_; i += 32) mx = fmaxf(mx, S[r][i]);
        #pragma unroll
        for (int off = 1; off < 32; off <<= 1) mx = fmaxf(mx, __shfl_xor(mx, off, 64));
        float sum = 0.f;
        for (int i = cx; i < L_; i += 32) {
            const float sv = S[r][i];
            const float e = (sv == -1e32f) ? 0.f : __expf(sv - mx);
            S[r][i] = e;
            sum += e;
        }
        #pragma unroll
        for (int off = 1; off < 32; off <<= 1) sum += __shfl_xor(sum, off, 64);
        if (cx == 0) invs[r] = (sum > 0.f) ? (1.0f / sum) : 0.f;  // all-masked row -> p = 0
    }
    __syncthreads();

    // ---- normalize in LDS + coalesced float4 write of attn ----
    {
        float* dst = attn_out + ((size_t)(h*B_ + b) * L_ + q0) * L_;
        #pragma unroll
        for (int i = 0; i < 8; i++) {
            const float iv = invs[i];
            float4 pv = *(const float4*)&S[i][t*4];
            pv.x *= iv; pv.y *= iv; pv.z *= iv; pv.w *= iv;
            *(float4*)&S[i][t*4] = pv;
            *(float4*)(dst + (size_t)i * L_ + t*4) = pv;
        }
    }
    __syncthreads();

    // ---- PV ----
    const int dbase = cx * 2;
    float c0 = 0.f, c1 = 0.f;
    for (int k0 = 0; k0 < L_; k0 += 64) {
        {
            const int kk = t >> 2, db = (t & 3) * 16;
            const float* src = vh + (size_t)(b*L_ + k0 + kk) * D_ + h*64 + db;
            float4 v0 = *(const float4*)(src + 0);
            float4 v1 = *(const float4*)(src + 4);
            float4 v2 = *(const float4*)(src + 8);
            float4 v3 = *(const float4*)(src + 12);
            *(float4*)&KVs[kk][db +  0] = v0;
            *(float4*)&KVs[kk][db +  4] = v1;
            *(float4*)&KVs[kk][db +  8] = v2;
            *(float4*)&KVs[kk][db + 12] = v3;
        }
        __syncthreads();
        #pragma unroll
        for (int kk = 0; kk < 64; kk += 4) {
            const float4 pv = *(const float4*)&S[r][k0+kk];
            const float2 v0 = *(const float2*)&KVs[kk+0][dbase];
            const float2 v1 = *(const float2*)&KVs[kk+1][dbase];
            const float2 v2 = *(const float2*)&KVs[kk+2][dbase];
            const float2 v3 = *(const float2*)&KVs[kk+3][dbase];
            c0 += pv.x*v0.x + pv.y*v1.x + pv.z*v2.x + pv.w*v3.x;
            c1 += pv.x*v0.y + pv.y*v1.y + pv.z*v2.y + pv.w*v3.y;
        }
        __syncthreads();
    }
    *(float2*)(ctx + (size_t)(b*L_ + q0 + r) * D_ + h*64 + dbase) = make_float2(c0, c1);
}

extern "C" void kernel_launch(void* const* d_in, const int* in_sizes, int n_in,
                              void* d_out, int out_size, void* d_ws, size_t ws_size,
                              hipStream_t stream)
{
    const float* q    = (const float*)d_in[0];
    const float* k    = (const float*)d_in[1];
    const float* v    = (const float*)d_in[2];
    const int*   mask = (const int*)d_in[4];
    const float* ln1w = (const float*)d_in[5];
    const float* ln1b = (const float*)d_in[6];
    const float* ln2w = (const float*)d_in[7];
    const float* ln2b = (const float*)d_in[8];
    const float* ln3w = (const float*)d_in[9];
    const float* ln3b = (const float*)d_in[10];
    const float* wq   = (const float*)d_in[11];
    const float* wk   = (const float*)d_in[12];
    const float* wv   = (const float*)d_in[13];
    const float* wfc  = (const float*)d_in[14];

    float* dyn_out  = (float*)d_out;                       // [B, L, D]
    float* attn_out = dyn_out + (size_t)B_ * L_ * D_;      // [H*B, L, L]

    float* ws    = (float*)d_ws;
    float* stats = ws;                                     // 3 * NROWS_ * 2 floats
    float* qh    = stats + (size_t)3 * NROWS_ * 2;
    float* kh    = qh + (size_t)NROWS_ * D_;
    float* vh    = kh + (size_t)NROWS_ * D_;
    float* ctx   = vh + (size_t)NROWS_ * D_;
    // total ws use: 24576 + 4*4194304 floats = ~67.2 MB

    ln_stats_kernel<<<dim3(NROWS_, 3), 256, 0, stream>>>(q, k, v, stats);

    dim3 pg(NROWS_ / 128, D_ / 128);
    gemm_nt_kernel<<<pg, 256, 0, stream>>>(q, wq, stats + (size_t)0*NROWS_*2, ln1w, ln1b, qh, NROWS_, D_, D_, 1);
    gemm_nt_kernel<<<pg, 256, 0, stream>>>(k, wk, stats + (size_t)1*NROWS_*2, ln2w, ln2b, kh, NROWS_, D_, D_, 1);
    gemm_nt_kernel<<<pg, 256, 0, stream>>>(v, wv, stats + (size_t)2*NROWS_*2, ln3w, ln3b, vh, NROWS_, D_, D_, 1);

    attn_kernel<<<dim3(L_/8, H_, B_), 256, 0, stream>>>(qh, kh, vh, mask, attn_out, ctx);

    gemm_nt_kernel<<<pg, 256, 0, stream>>>(ctx, wfc, nullptr, nullptr, nullptr, dyn_out, NROWS_, D_, D_, 0);
}

// Round 2
// 368.717 us; speedup vs baseline: 4.2089x; 4.2089x over previous
//
#include <hip/hip_runtime.h>
#include <hip/hip_bf16.h>

#define B_ 4
#define L_ 1024
#define D_ 1024
#define H_ 16
#define NROWS_ (B_ * L_)   // 4096

typedef __attribute__((ext_vector_type(8))) short short8;
typedef __attribute__((ext_vector_type(4))) float f32x4;

__device__ inline ushort f2bf(float f) {
    union { float f; uint u; } x; x.f = f;
    return (ushort)((x.u + 0x7fffu + ((x.u >> 16) & 1u)) >> 16);
}
__device__ inline short8 pack8(float4 a, float4 b) {
    short8 r;
    r[0]=(short)f2bf(a.x); r[1]=(short)f2bf(a.y); r[2]=(short)f2bf(a.z); r[3]=(short)f2bf(a.w);
    r[4]=(short)f2bf(b.x); r[5]=(short)f2bf(b.y); r[6]=(short)f2bf(b.z); r[7]=(short)f2bf(b.w);
    return r;
}

// ---------------- LayerNorm row stats (mean, rstd) ----------------
__global__ __launch_bounds__(256) void ln_stats_kernel(
    const float* __restrict__ q, const float* __restrict__ k, const float* __restrict__ v,
    float* __restrict__ stats)
{
    const int row = blockIdx.x;
    const int which = blockIdx.y;
    const float* x = (which == 0 ? q : (which == 1 ? k : v)) + (size_t)row * D_;
    const int tid = threadIdx.x;
    float4 t4 = ((const float4*)x)[tid];
    float s  = t4.x + t4.y + t4.z + t4.w;
    float s2 = t4.x*t4.x + t4.y*t4.y + t4.z*t4.z + t4.w*t4.w;
    #pragma unroll
    for (int off = 1; off < 64; off <<= 1) {
        s  += __shfl_xor(s,  off, 64);
        s2 += __shfl_xor(s2, off, 64);
    }
    __shared__ float red[8];
    const int wid = tid >> 6;
    if ((tid & 63) == 0) { red[wid*2] = s; red[wid*2+1] = s2; }
    __syncthreads();
    if (tid == 0) {
        s  = red[0] + red[2] + red[4] + red[6];
        s2 = red[1] + red[3] + red[5] + red[7];
        const float mean = s * (1.0f/(float)D_);
        const float var  = s2 * (1.0f/(float)D_) - mean*mean;
        float* st = stats + ((size_t)which * NROWS_ + row) * 2;
        st[0] = mean;
        st[1] = rsqrtf(var + 1e-5f);
    }
}

// ---------------- mask -> bitmask (bit set = masked) ----------------
__global__ __launch_bounds__(256) void maskbits_kernel(
    const int* __restrict__ mask, uint* __restrict__ mbits)
{
    const size_t i = (size_t)blockIdx.x * 256 + threadIdx.x;
    const int m = mask[i];
    unsigned long long bal = __ballot(m != 0);
    const int lane = threadIdx.x & 63;
    if (lane == 0)       mbits[i >> 5] = (uint)bal;
    else if (lane == 32) mbits[i >> 5] = (uint)(bal >> 32);
}

// ---------------- MFMA GEMM: C = op(A) @ W^T  (M=4096, N=K=1024) ----------------
// AMODE 0: A fp32 + fused LN -> bf16 ; AMODE 1: A already bf16
// OMODE 0: bf16 out [b][h][seq][64] ; OMODE 1: bf16 out [b][h][d][seq] ; OMODE 2: fp32 [M][N]
template<int AMODE, int OMODE>
__global__ __launch_bounds__(256) void mm_kernel(
    const void* __restrict__ Av, const float* __restrict__ W,
    const float* __restrict__ stats, const float* __restrict__ lnw, const float* __restrict__ lnb,
    void* __restrict__ Cv)
{
    constexpr int K = 1024, N = 1024;
    __shared__ short As[128*40];
    __shared__ short Ws[128*40];
    const int tid = threadIdx.x;
    const int bm = blockIdx.x * 128, bn = blockIdx.y * 128;
    const int srow = tid >> 1, skq = (tid & 1) * 16;
    float mu = 0.f, rstd = 0.f;
    if (AMODE == 0) { mu = stats[(size_t)(bm+srow)*2]; rstd = stats[(size_t)(bm+srow)*2+1]; }
    const int w = tid >> 6, lane = tid & 63;
    const int wr = w >> 1, wc = w & 1;
    const int lc = lane & 15, g = lane >> 4;
    f32x4 acc[4][4] = {};
    const float*  Af = (const float*)Av;
    const ushort* Ab = (const ushort*)Av;

    for (int k0 = 0; k0 < K; k0 += 32) {
        if (AMODE == 0) {
            const float* ap = Af + (size_t)(bm+srow)*K + k0 + skq;
            float4 a0 = *(const float4*)(ap+0), a1 = *(const float4*)(ap+4);
            float4 a2 = *(const float4*)(ap+8), a3 = *(const float4*)(ap+12);
            const float4 w0 = *(const float4*)(lnw+k0+skq+0), w1 = *(const float4*)(lnw+k0+skq+4);
            const float4 w2 = *(const float4*)(lnw+k0+skq+8), w3 = *(const float4*)(lnw+k0+skq+12);
            const float4 b0 = *(const float4*)(lnb+k0+skq+0), b1 = *(const float4*)(lnb+k0+skq+4);
            const float4 b2 = *(const float4*)(lnb+k0+skq+8), b3 = *(const float4*)(lnb+k0+skq+12);
            a0.x=(a0.x-mu)*rstd*w0.x+b0.x; a0.y=(a0.y-mu)*rstd*w0.y+b0.y; a0.z=(a0.z-mu)*rstd*w0.z+b0.z; a0.w=(a0.w-mu)*rstd*w0.w+b0.w;
            a1.x=(a1.x-mu)*rstd*w1.x+b1.x; a1.y=(a1.y-mu)*rstd*w1.y+b1.y; a1.z=(a1.z-mu)*rstd*w1.z+b1.z; a1.w=(a1.w-mu)*rstd*w1.w+b1.w;
            a2.x=(a2.x-mu)*rstd*w2.x+b2.x; a2.y=(a2.y-mu)*rstd*w2.y+b2.y; a2.z=(a2.z-mu)*rstd*w2.z+b2.z; a2.w=(a2.w-mu)*rstd*w2.w+b2.w;
            a3.x=(a3.x-mu)*rstd*w3.x+b3.x; a3.y=(a3.y-mu)*rstd*w3.y+b3.y; a3.z=(a3.z-mu)*rstd*w3.z+b3.z; a3.w=(a3.w-mu)*rstd*w3.w+b3.w;
            *(short8*)&As[srow*40 + skq + 0] = pack8(a0, a1);
            *(short8*)&As[srow*40 + skq + 8] = pack8(a2, a3);
        } else {
            const ushort* ap = Ab + (size_t)(bm+srow)*K + k0 + skq;
            *(short8*)&As[srow*40 + skq + 0] = *(const short8*)(ap + 0);
            *(short8*)&As[srow*40 + skq + 8] = *(const short8*)(ap + 8);
        }
        {
            const float* wp = W + (size_t)(bn+srow)*K + k0 + skq;
            float4 a0 = *(const float4*)(wp+0), a1 = *(const float4*)(wp+4);
            float4 a2 = *(const float4*)(wp+8), a3 = *(const float4*)(wp+12);
            *(short8*)&Ws[srow*40 + skq + 0] = pack8(a0, a1);
            *(short8*)&Ws[srow*40 + skq + 8] = pack8(a2, a3);
        }
        __syncthreads();
        short8 af[4], bfr[4];
        #pragma unroll
        for (int mi = 0; mi < 4; mi++) af[mi]  = *(const short8*)&As[(wr*64+mi*16+lc)*40 + g*8];
        #pragma unroll
        for (int ni = 0; ni < 4; ni++) bfr[ni] = *(const short8*)&Ws[(wc*64+ni*16+lc)*40 + g*8];
        #pragma unroll
        for (int mi = 0; mi < 4; mi++)
            #pragma unroll
            for (int ni = 0; ni < 4; ni++)
                acc[mi][ni] = __builtin_amdgcn_mfma_f32_16x16x32_bf16(af[mi], bfr[ni], acc[mi][ni], 0, 0, 0);
        __syncthreads();
    }

    #pragma unroll
    for (int mi = 0; mi < 4; mi++)
        #pragma unroll
        for (int ni = 0; ni < 4; ni++)
            #pragma unroll
            for (int r = 0; r < 4; r++) {
                const int m = bm + wr*64 + mi*16 + g*4 + r;
                const int n = bn + wc*64 + ni*16 + lc;
                const float val = acc[mi][ni][r];
                if (OMODE == 2) {
                    ((float*)Cv)[(size_t)m*N + n] = val;
                } else {
                    const int bb = m >> 10, seq = m & 1023, hh = n >> 6, d = n & 63;
                    size_t idx;
                    if (OMODE == 0) idx = (((size_t)(bb*16+hh))*1024 + seq)*64 + d;
                    else            idx = (((size_t)(bb*16+hh))*64 + d)*1024 + seq;
                    ((ushort*)Cv)[idx] = f2bf(val);
                }
            }
}

// ---------------- MFMA attention ----------------
// block: 64 q-rows of one (b,h); 4 waves x 16 rows. Two-pass stable softmax.
__global__ __launch_bounds__(256) void attn_mfma_kernel(
    const ushort* __restrict__ qh, const ushort* __restrict__ kh, const ushort* __restrict__ vt,
    const uint* __restrict__ mbits, float* __restrict__ p_out, ushort* __restrict__ ctx)
{
    __shared__ short Qs[64*72];
    __shared__ short Ks[64*72];
    __shared__ short Vts[64*72];
    __shared__ uint  Ms[64*32];
    __shared__ short Pb[4][16*72];
    const int t = threadIdx.x;
    const int q0 = blockIdx.x * 64, h = blockIdx.y, b = blockIdx.z;
    const int w = t >> 6, lane = t & 63, lc = lane & 15, g = lane >> 4;

    const ushort* qbase = qh + ((size_t)(b*16+h)*1024 + q0)*64;
    const ushort* kbase = kh + (size_t)(b*16+h)*1024*64;
    const ushort* vbase = vt + (size_t)(b*16+h)*64*1024;

    {   // stage Q (64x64 bf16) and mask words (64x32 u32)
        const int row = t >> 2, seg = (t & 3) * 16;
        *(short8*)&Qs[row*72+seg+0] = *(const short8*)(qbase + row*64 + seg + 0);
        *(short8*)&Qs[row*72+seg+8] = *(const short8*)(qbase + row*64 + seg + 8);
        const int wq = (t & 3) * 8;
        const uint* mrow = mbits + ((size_t)b*1024 + q0 + row)*32 + wq;
        *(uint4*)&Ms[row*32+wq+0] = *(const uint4*)(mrow + 0);
        *(uint4*)&Ms[row*32+wq+4] = *(const uint4*)(mrow + 4);
    }
    __syncthreads();

    const int qrow = w * 16;
    const short8 aq0 = *(const short8*)&Qs[(qrow+lc)*72 + 0  + g*8];
    const short8 aq1 = *(const short8*)&Qs[(qrow+lc)*72 + 32 + g*8];

    float m_run[4] = {-3e38f,-3e38f,-3e38f,-3e38f};
    float s_run[4] = {0.f,0.f,0.f,0.f};

    // ---- pass 1: online max & sum ----
    for (int kt = 0; kt < 16; kt++) {
        {
            const int row = t >> 2, seg = (t & 3) * 16;
            *(short8*)&Ks[row*72+seg+0] = *(const short8*)(kbase + (size_t)(kt*64+row)*64 + seg + 0);
            *(short8*)&Ks[row*72+seg+8] = *(const short8*)(kbase + (size_t)(kt*64+row)*64 + seg + 8);
        }
        __syncthreads();
        f32x4 sacc[4];
        #pragma unroll
        for (int ni = 0; ni < 4; ni++) {
            const short8 b0 = *(const short8*)&Ks[(ni*16+lc)*72 + 0  + g*8];
            const short8 b1 = *(const short8*)&Ks[(ni*16+lc)*72 + 32 + g*8];
            f32x4 z = {0.f,0.f,0.f,0.f};
            z = __builtin_amdgcn_mfma_f32_16x16x32_bf16(aq0, b0, z, 0, 0, 0);
            z = __builtin_amdgcn_mfma_f32_16x16x32_bf16(aq1, b1, z, 0, 0, 0);
            sacc[ni] = z;
        }
        #pragma unroll
        for (int r = 0; r < 4; r++) {
            const int q = qrow + g*4 + r;
            const uint w0 = Ms[q*32 + kt*2], w1 = Ms[q*32 + kt*2 + 1];
            float sv[4];
            float tm = -3e38f;
            #pragma unroll
            for (int ni = 0; ni < 4; ni++) {
                const uint word = (ni < 2) ? w0 : w1;
                const bool msk = (word >> ((ni & 1)*16 + lc)) & 1u;
                const float s = msk ? -3e38f : sacc[ni][r];
                sv[ni] = s;
                tm = fmaxf(tm, s);
            }
            #pragma unroll
            for (int off = 1; off < 16; off <<= 1) tm = fmaxf(tm, __shfl_xor(tm, off, 64));
            const float mn = fmaxf(m_run[r], tm);
            float es = 0.f;
            #pragma unroll
            for (int ni = 0; ni < 4; ni++)
                es += (sv[ni] == -3e38f) ? 0.f : __expf((sv[ni] - mn) * 0.125f);
            #pragma unroll
            for (int off = 1; off < 16; off <<= 1) es += __shfl_xor(es, off, 64);
            const float scale = __expf((m_run[r] - mn) * 0.125f);
            s_run[r] = s_run[r] * scale + es;
            m_run[r] = mn;
        }
        __syncthreads();
    }

    float inv[4];
    #pragma unroll
    for (int r = 0; r < 4; r++) inv[r] = (s_run[r] > 0.f) ? (1.0f / s_run[r]) : 0.f;

    // ---- pass 2: recompute S, write p, accumulate PV ----
    f32x4 cacc[4] = {{0,0,0,0},{0,0,0,0},{0,0,0,0},{0,0,0,0}};
    float* pblk = p_out + ((size_t)(h*B_ + b)*1024 + q0)*1024;
    for (int kt = 0; kt < 16; kt++) {
        {
            const int row = t >> 2, seg = (t & 3) * 16;
            *(short8*)&Ks[row*72+seg+0]  = *(const short8*)(kbase + (size_t)(kt*64+row)*64 + seg + 0);
            *(short8*)&Ks[row*72+seg+8]  = *(const short8*)(kbase + (size_t)(kt*64+row)*64 + seg + 8);
            *(short8*)&Vts[row*72+seg+0] = *(const short8*)(vbase + (size_t)row*1024 + kt*64 + seg + 0);
            *(short8*)&Vts[row*72+seg+8] = *(const short8*)(vbase + (size_t)row*1024 + kt*64 + seg + 8);
        }
        __syncthreads();
        f32x4 sacc[4];
        #pragma unroll
        for (int ni = 0; ni < 4; ni++) {
            const short8 b0 = *(const short8*)&Ks[(ni*16+lc)*72 + 0  + g*8];
            const short8 b1 = *(const short8*)&Ks[(ni*16+lc)*72 + 32 + g*8];
            f32x4 z = {0.f,0.f,0.f,0.f};
            z = __builtin_amdgcn_mfma_f32_16x16x32_bf16(aq0, b0, z, 0, 0, 0);
            z = __builtin_amdgcn_mfma_f32_16x16x32_bf16(aq1, b1, z, 0, 0, 0);
            sacc[ni] = z;
        }
        #pragma unroll
        for (int r = 0; r < 4; r++) {
            const int q = qrow + g*4 + r;
            const uint w0 = Ms[q*32 + kt*2], w1 = Ms[q*32 + kt*2 + 1];
            float* prow = pblk + (size_t)q*1024 + kt*64;
            #pragma unroll
            for (int ni = 0; ni < 4; ni++) {
                const uint word = (ni < 2) ? w0 : w1;
                const bool msk = (word >> ((ni & 1)*16 + lc)) & 1u;
                const float p = msk ? 0.f : __expf((sacc[ni][r] - m_run[r]) * 0.125f) * inv[r];
                prow[ni*16 + lc] = p;
                Pb[w][(g*4+r)*72 + ni*16 + lc] = (short)f2bf(p);
            }
        }
        const short8 pa0 = *(const short8*)&Pb[w][lc*72 + 0  + g*8];
        const short8 pa1 = *(const short8*)&Pb[w][lc*72 + 32 + g*8];
        #pragma unroll
        for (int di = 0; di < 4; di++) {
            const short8 vb0 = *(const short8*)&Vts[(di*16+lc)*72 + 0  + g*8];
            const short8 vb1 = *(const short8*)&Vts[(di*16+lc)*72 + 32 + g*8];
            cacc[di] = __builtin_amdgcn_mfma_f32_16x16x32_bf16(pa0, vb0, cacc[di], 0, 0, 0);
            cacc[di] = __builtin_amdgcn_mfma_f32_16x16x32_bf16(pa1, vb1, cacc[di], 0, 0, 0);
        }
        __syncthreads();
    }

    // ctx bf16 [b*1024+q][h*64+d]
    #pragma unroll
    for (int di = 0; di < 4; di++)
        #pragma unroll
        for (int r = 0; r < 4; r++) {
            const int q = qrow + g*4 + r;
            ctx[((size_t)b*1024 + q0 + q)*1024 + h*64 + di*16 + lc] = f2bf(cacc[di][r]);
        }
}

extern "C" void kernel_launch(void* const* d_in, const int* in_sizes, int n_in,
                              void* d_out, int out_size, void* d_ws, size_t ws_size,
                              hipStream_t stream)
{
    const float* q    = (const float*)d_in[0];
    const float* k    = (const float*)d_in[1];
    const float* v    = (const float*)d_in[2];
    const int*   mask = (const int*)d_in[4];
    const float* ln1w = (const float*)d_in[5];
    const float* ln1b = (const float*)d_in[6];
    const float* ln2w = (const float*)d_in[7];
    const float* ln2b = (const float*)d_in[8];
    const float* ln3w = (const float*)d_in[9];
    const float* ln3b = (const float*)d_in[10];
    const float* wq   = (const float*)d_in[11];
    const float* wk   = (const float*)d_in[12];
    const float* wv   = (const float*)d_in[13];
    const float* wfc  = (const float*)d_in[14];

    float* dyn_out  = (float*)d_out;                       // [B, L, D]
    float* attn_out = dyn_out + (size_t)B_ * L_ * D_;      // [H*B, L, L]

    char* ws = (char*)d_ws;
    float*  stats = (float*)ws;                                  ws += (size_t)3 * NROWS_ * 2 * 4;
    uint*   mbits = (uint*)ws;                                   ws += (size_t)B_ * L_ * (L_/32) * 4;
    ushort* qh    = (ushort*)ws;                                 ws += (size_t)NROWS_ * D_ * 2;
    ushort* kh    = (ushort*)ws;                                 ws += (size_t)NROWS_ * D_ * 2;
    ushort* vt    = (ushort*)ws;                                 ws += (size_t)NROWS_ * D_ * 2;
    ushort* ctx   = (ushort*)ws;                                 ws += (size_t)NROWS_ * D_ * 2;

    ln_stats_kernel<<<dim3(NROWS_, 3), 256, 0, stream>>>(q, k, v, stats);
    maskbits_kernel<<<(B_*L_*L_)/256, 256, 0, stream>>>(mask, mbits);

    dim3 pg(NROWS_/128, D_/128);
    mm_kernel<0,0><<<pg, 256, 0, stream>>>(q, wq, stats + (size_t)0*NROWS_*2, ln1w, ln1b, qh);
    mm_kernel<0,0><<<pg, 256, 0, stream>>>(k, wk, stats + (size_t)1*NROWS_*2, ln2w, ln2b, kh);
    mm_kernel<0,1><<<pg, 256, 0, stream>>>(v, wv, stats + (size_t)2*NROWS_*2, ln3w, ln3b, vt);

    attn_mfma_kernel<<<dim3(L_/64, H_, B_), 256, 0, stream>>>(qh, kh, vt, mbits, attn_out, ctx);

    mm_kernel<1,2><<<pg, 256, 0, stream>>>(ctx, wfc, nullptr, nullptr, nullptr, dyn_out);
}

// Round 3
// 226.514 us; speedup vs baseline: 6.8512x; 1.6278x over previous
//
#include <hip/hip_runtime.h>
#include <hip/hip_bf16.h>

#define B_ 4
#define L_ 1024
#define D_ 1024
#define H_ 16
#define NROWS_ (B_ * L_)   // 4096

typedef __attribute__((ext_vector_type(8))) short short8;
typedef __attribute__((ext_vector_type(4))) float f32x4;

__device__ __forceinline__ ushort f2bf(float f) {   // RNE
    union { float f; uint u; } x; x.f = f;
    return (ushort)((x.u + 0x7fffu + ((x.u >> 16) & 1u)) >> 16);
}
__device__ __forceinline__ ushort f2bf_hup(float f) {  // round-half-up (cheap)
    union { float f; uint u; } x; x.f = f;
    return (ushort)((x.u + 0x8000u) >> 16);
}
__device__ __forceinline__ void gl_lds16(const void* g, void* l) {
    __builtin_amdgcn_global_load_lds(
        (const __attribute__((address_space(1))) uint*)(uintptr_t)g,
        (__attribute__((address_space(3))) uint*)(uintptr_t)l, 16, 0, 0);
}

// ---------------- fused LayerNorm -> bf16 ----------------
__global__ __launch_bounds__(256) void ln_norm_kernel(
    const float* __restrict__ q, const float* __restrict__ k, const float* __restrict__ v,
    const float* __restrict__ ln1w, const float* __restrict__ ln1b,
    const float* __restrict__ ln2w, const float* __restrict__ ln2b,
    const float* __restrict__ ln3w, const float* __restrict__ ln3b,
    ushort* __restrict__ qn, ushort* __restrict__ kn, ushort* __restrict__ vn)
{
    const int row = blockIdx.x, which = blockIdx.y, t = threadIdx.x;
    const float *x, *lw, *lb; ushort* out;
    if (which == 0)      { x = q; lw = ln1w; lb = ln1b; out = qn; }
    else if (which == 1) { x = k; lw = ln2w; lb = ln2b; out = kn; }
    else                 { x = v; lw = ln3w; lb = ln3b; out = vn; }
    x += (size_t)row * D_; out += (size_t)row * D_;
    const float4 t4 = ((const float4*)x)[t];
    float s  = t4.x + t4.y + t4.z + t4.w;
    float s2 = t4.x*t4.x + t4.y*t4.y + t4.z*t4.z + t4.w*t4.w;
    #pragma unroll
    for (int off = 1; off < 64; off <<= 1) {
        s  += __shfl_xor(s,  off, 64);
        s2 += __shfl_xor(s2, off, 64);
    }
    __shared__ float red[8];
    __shared__ float mr[2];
    const int wid = t >> 6;
    if ((t & 63) == 0) { red[wid*2] = s; red[wid*2+1] = s2; }
    __syncthreads();
    if (t == 0) {
        s  = red[0] + red[2] + red[4] + red[6];
        s2 = red[1] + red[3] + red[5] + red[7];
        const float mean = s * (1.0f/(float)D_);
        const float var  = s2 * (1.0f/(float)D_) - mean*mean;
        mr[0] = mean; mr[1] = rsqrtf(var + 1e-5f);
    }
    __syncthreads();
    const float mean = mr[0], rstd = mr[1];
    const float4 w4 = ((const float4*)lw)[t];
    const float4 b4 = ((const float4*)lb)[t];
    ushort4 o;
    o.x = f2bf((t4.x - mean)*rstd*w4.x + b4.x);
    o.y = f2bf((t4.y - mean)*rstd*w4.y + b4.y);
    o.z = f2bf((t4.z - mean)*rstd*w4.z + b4.z);
    o.w = f2bf((t4.w - mean)*rstd*w4.w + b4.w);
    ((ushort4*)out)[t] = o;
}

// ---------------- weights fp32 -> bf16 ----------------
__global__ __launch_bounds__(256) void wcvt_kernel(
    const float* __restrict__ w0, const float* __restrict__ w1,
    const float* __restrict__ w2, const float* __restrict__ w3,
    ushort* __restrict__ o0, ushort* __restrict__ o1,
    ushort* __restrict__ o2, ushort* __restrict__ o3)
{
    const int which = blockIdx.y;
    const float* src = which == 0 ? w0 : which == 1 ? w1 : which == 2 ? w2 : w3;
    ushort* dst      = which == 0 ? o0 : which == 1 ? o1 : which == 2 ? o2 : o3;
    const size_t i = (size_t)blockIdx.x * 256 + threadIdx.x;
    const float4 f = ((const float4*)src)[i];
    ushort4 o; o.x = f2bf(f.x); o.y = f2bf(f.y); o.z = f2bf(f.z); o.w = f2bf(f.w);
    ((ushort4*)dst)[i] = o;
}

// ---------------- mask -> bitmask (bit set = masked) ----------------
__global__ __launch_bounds__(256) void maskbits_kernel(
    const int* __restrict__ mask, uint* __restrict__ mbits)
{
    const size_t i = (size_t)blockIdx.x * 256 + threadIdx.x;
    const int m = mask[i];
    unsigned long long bal = __ballot(m != 0);
    const int lane = threadIdx.x & 63;
    if (lane == 0)       mbits[i >> 5] = (uint)bal;
    else if (lane == 32) mbits[i >> 5] = (uint)(bal >> 32);
}

// ---------------- bf16 MFMA GEMM with global_load_lds, 128x128 tile, BK=64 ----------------
// C[m][n] = A[m,:] . B[n,:]  (both row pitch 1024, K=1024)
// OMODE 0: bf16 out at [b][h][seq][64] from (m=seq-ish, n=h*64+d)
// OMODE 1: bf16 out at [b][h][d][seq]  from (m=h*64+d,  n=b*1024+seq)
// OMODE 2: fp32 out row-major [m][1024]
template<int OMODE>
__global__ __launch_bounds__(256) void mm_kernel(
    const ushort* __restrict__ A, const ushort* __restrict__ Bw, void* __restrict__ Cv)
{
    __shared__ __align__(16) ushort As[128*64];
    __shared__ __align__(16) ushort Bs[128*64];
    const int t = threadIdx.x, w = t >> 6, lane = t & 63;
    const int lc = lane & 15, g = lane >> 4;
    const int wr = w >> 1, wc = w & 1;
    const int bm = blockIdx.x * 128, bn = blockIdx.y * 128;
    const int srow = lane >> 3, sp = lane & 7;
    f32x4 acc[4][4] = {};

    for (int k0 = 0; k0 < 1024; k0 += 64) {
        #pragma unroll
        for (int j = 0; j < 4; j++) {
            const int i = w*4 + j;              // 16 chunks of 8 rows
            const int row = i*8 + srow;
            const int c = (sp - (row & 7)) & 7; // inverse swizzle on global source
            gl_lds16(A  + (size_t)(bm+row)*1024 + k0 + c*8, &As[i*512]);
            gl_lds16(Bw + (size_t)(bn+row)*1024 + k0 + c*8, &Bs[i*512]);
        }
        __syncthreads();
        #pragma unroll
        for (int ks = 0; ks < 2; ks++) {
            short8 af[4], bf4[4];
            #pragma unroll
            for (int mi = 0; mi < 4; mi++) {
                const int row = wr*64 + mi*16 + lc;
                af[mi] = *(const short8*)&As[row*64 + (((ks*4+g) + (row&7)) & 7)*8];
            }
            #pragma unroll
            for (int ni = 0; ni < 4; ni++) {
                const int row = wc*64 + ni*16 + lc;
                bf4[ni] = *(const short8*)&Bs[row*64 + (((ks*4+g) + (row&7)) & 7)*8];
            }
            #pragma unroll
            for (int mi = 0; mi < 4; mi++)
                #pragma unroll
                for (int ni = 0; ni < 4; ni++)
                    acc[mi][ni] = __builtin_amdgcn_mfma_f32_16x16x32_bf16(af[mi], bf4[ni], acc[mi][ni], 0, 0, 0);
        }
        __syncthreads();
    }

    #pragma unroll
    for (int mi = 0; mi < 4; mi++)
        #pragma unroll
        for (int ni = 0; ni < 4; ni++)
            #pragma unroll
            for (int r = 0; r < 4; r++) {
                const int m = bm + wr*64 + mi*16 + g*4 + r;
                const int n = bn + wc*64 + ni*16 + lc;
                const float val = acc[mi][ni][r];
                if (OMODE == 2) {
                    ((float*)Cv)[(size_t)m*1024 + n] = val;
                } else if (OMODE == 0) {
                    const int bb = m >> 10, seq = m & 1023, hh = n >> 6, d = n & 63;
                    ((ushort*)Cv)[(((size_t)(bb*16+hh))*1024 + seq)*64 + d] = f2bf(val);
                } else {
                    const int bb = n >> 10, seq = n & 1023, hh = m >> 6, d = m & 63;
                    ((ushort*)Cv)[((size_t)(bb*16+hh))*65536 + (size_t)d*1024 + seq] = f2bf(val);
                }
            }
}

// ---------------- MFMA attention, fixed-max softmax, two QK^T passes ----------------
__global__ __launch_bounds__(256) void attn_kernel(
    const ushort* __restrict__ qh, const ushort* __restrict__ kh, const ushort* __restrict__ vt,
    const uint* __restrict__ mbits, float* __restrict__ p_out, ushort* __restrict__ ctx)
{
    __shared__ __align__(16) ushort Qs[64*72];
    __shared__ __align__(16) ushort Ks[64*64];
    __shared__ __align__(16) ushort Vs[64*64];
    __shared__ __align__(16) ushort Pb[4][16*72];
    __shared__ uint Ms[64*32];
    const int t = threadIdx.x, w = t >> 6, lane = t & 63;
    const int lc = lane & 15, g = lane >> 4;
    const int q0 = blockIdx.x * 64, h = blockIdx.y, b = blockIdx.z;
    const ushort* qbase = qh + ((size_t)(b*16+h)*1024 + q0)*64;
    const ushort* kbase = kh + (size_t)(b*16+h)*1024*64;
    const ushort* vbase = vt + (size_t)(b*16+h)*64*1024;

    {   // stage Q (padded 72) + mask words
        const int row = t >> 2, seg = (t & 3) * 16;
        *(short8*)&Qs[row*72+seg+0] = *(const short8*)(qbase + (size_t)row*64 + seg + 0);
        *(short8*)&Qs[row*72+seg+8] = *(const short8*)(qbase + (size_t)row*64 + seg + 8);
        const int wq = (t & 3) * 8;
        const uint* mrow = mbits + ((size_t)b*1024 + q0 + row)*32 + wq;
        *(uint4*)&Ms[row*32+wq+0] = *(const uint4*)(mrow + 0);
        *(uint4*)&Ms[row*32+wq+4] = *(const uint4*)(mrow + 4);
    }
    __syncthreads();

    const int qrow = w * 16;
    const short8 aq0 = *(const short8*)&Qs[(qrow+lc)*72 + g*8];
    const short8 aq1 = *(const short8*)&Qs[(qrow+lc)*72 + 32 + g*8];
    const int srow = lane >> 3, sp = lane & 7;

    float s_part[4] = {0.f, 0.f, 0.f, 0.f};

    // ---- pass 1: row sums of masked exp(s/8) ----
    for (int kt = 0; kt < 16; kt++) {
        #pragma unroll
        for (int j = 0; j < 2; j++) {
            const int i = w*2 + j;
            const int row = i*8 + srow;
            const int c = (sp - (row & 7)) & 7;
            gl_lds16(kbase + ((size_t)(kt*64+row))*64 + c*8, &Ks[i*512]);
        }
        __syncthreads();
        f32x4 sacc[4];
        #pragma unroll
        for (int ni = 0; ni < 4; ni++) {
            const int row = ni*16 + lc;
            const short8 b0 = *(const short8*)&Ks[row*64 + (((g  ) + (row&7)) & 7)*8];
            const short8 b1 = *(const short8*)&Ks[row*64 + (((4+g) + (row&7)) & 7)*8];
            f32x4 z = {0.f,0.f,0.f,0.f};
            z = __builtin_amdgcn_mfma_f32_16x16x32_bf16(aq0, b0, z, 0, 0, 0);
            z = __builtin_amdgcn_mfma_f32_16x16x32_bf16(aq1, b1, z, 0, 0, 0);
            sacc[ni] = z;
        }
        #pragma unroll
        for (int r = 0; r < 4; r++) {
            const int qq = qrow + g*4 + r;
            const uint w0 = Ms[qq*32 + kt*2], w1 = Ms[qq*32 + kt*2 + 1];
            #pragma unroll
            for (int ni = 0; ni < 4; ni++) {
                const uint word = (ni < 2) ? w0 : w1;
                const bool mk = (word >> ((ni & 1)*16 + lc)) & 1u;
                s_part[r] += mk ? 0.f : __expf(sacc[ni][r] * 0.125f);
            }
        }
        __syncthreads();
    }

    float inv[4];
    #pragma unroll
    for (int r = 0; r < 4; r++) {
        float s = s_part[r];
        #pragma unroll
        for (int off = 1; off < 16; off <<= 1) s += __shfl_xor(s, off, 64);
        inv[r] = (s > 0.f) ? (1.0f / s) : 0.f;
    }

    // ---- pass 2: recompute, write p = e*inv, PV on unnormalized e ----
    f32x4 cacc[4] = {{0,0,0,0},{0,0,0,0},{0,0,0,0},{0,0,0,0}};
    float* pblk = p_out + ((size_t)(h*B_ + b)*1024 + q0)*1024;
    for (int kt = 0; kt < 16; kt++) {
        #pragma unroll
        for (int j = 0; j < 2; j++) {
            const int i = w*2 + j;
            const int row = i*8 + srow;
            const int c = (sp - (row & 7)) & 7;
            gl_lds16(kbase + ((size_t)(kt*64+row))*64 + c*8, &Ks[i*512]);
            gl_lds16(vbase + (size_t)row*1024 + kt*64 + c*8, &Vs[i*512]);
        }
        __syncthreads();
        f32x4 sacc[4];
        #pragma unroll
        for (int ni = 0; ni < 4; ni++) {
            const int row = ni*16 + lc;
            const short8 b0 = *(const short8*)&Ks[row*64 + (((g  ) + (row&7)) & 7)*8];
            const short8 b1 = *(const short8*)&Ks[row*64 + (((4+g) + (row&7)) & 7)*8];
            f32x4 z = {0.f,0.f,0.f,0.f};
            z = __builtin_amdgcn_mfma_f32_16x16x32_bf16(aq0, b0, z, 0, 0, 0);
            z = __builtin_amdgcn_mfma_f32_16x16x32_bf16(aq1, b1, z, 0, 0, 0);
            sacc[ni] = z;
        }
        #pragma unroll
        for (int r = 0; r < 4; r++) {
            const int qq = qrow + g*4 + r;
            const uint w0 = Ms[qq*32 + kt*2], w1 = Ms[qq*32 + kt*2 + 1];
            float* prow = pblk + (size_t)qq*1024 + kt*64;
            #pragma unroll
            for (int ni = 0; ni < 4; ni++) {
                const uint word = (ni < 2) ? w0 : w1;
                const bool mk = (word >> ((ni & 1)*16 + lc)) & 1u;
                const float e = mk ? 0.f : __expf(sacc[ni][r] * 0.125f);
                prow[ni*16 + lc] = e * inv[r];
                Pb[w][(g*4+r)*72 + ni*16 + lc] = f2bf_hup(e);
            }
        }
        const short8 pa0 = *(const short8*)&Pb[w][lc*72 + g*8];
        const short8 pa1 = *(const short8*)&Pb[w][lc*72 + 32 + g*8];
        #pragma unroll
        for (int di = 0; di < 4; di++) {
            const int row = di*16 + lc;
            const short8 vb0 = *(const short8*)&Vs[row*64 + (((g  ) + (row&7)) & 7)*8];
            const short8 vb1 = *(const short8*)&Vs[row*64 + (((4+g) + (row&7)) & 7)*8];
            cacc[di] = __builtin_amdgcn_mfma_f32_16x16x32_bf16(pa0, vb0, cacc[di], 0, 0, 0);
            cacc[di] = __builtin_amdgcn_mfma_f32_16x16x32_bf16(pa1, vb1, cacc[di], 0, 0, 0);
        }
        __syncthreads();
    }

    #pragma unroll
    for (int di = 0; di < 4; di++)
        #pragma unroll
        for (int r = 0; r < 4; r++) {
            const int qq = qrow + g*4 + r;
            ctx[((size_t)b*1024 + q0 + qq)*1024 + h*64 + di*16 + lc] = f2bf(cacc[di][r] * inv[r]);
        }
}

extern "C" void kernel_launch(void* const* d_in, const int* in_sizes, int n_in,
                              void* d_out, int out_size, void* d_ws, size_t ws_size,
                              hipStream_t stream)
{
    const float* q    = (const float*)d_in[0];
    const float* k    = (const float*)d_in[1];
    const float* v    = (const float*)d_in[2];
    const int*   mask = (const int*)d_in[4];
    const float* ln1w = (const float*)d_in[5];
    const float* ln1b = (const float*)d_in[6];
    const float* ln2w = (const float*)d_in[7];
    const float* ln2b = (const float*)d_in[8];
    const float* ln3w = (const float*)d_in[9];
    const float* ln3b = (const float*)d_in[10];
    const float* wq   = (const float*)d_in[11];
    const float* wk   = (const float*)d_in[12];
    const float* wv   = (const float*)d_in[13];
    const float* wfc  = (const float*)d_in[14];

    float* dyn_out  = (float*)d_out;                       // [B, L, D]
    float* attn_out = dyn_out + (size_t)B_ * L_ * D_;      // [H*B, L, L]

    char* ws = (char*)d_ws;
    uint*   mbits = (uint*)ws;        ws += (size_t)B_ * L_ * (L_/32) * 4;   // 512 KB
    ushort* qn    = (ushort*)ws;      ws += (size_t)NROWS_ * D_ * 2;
    ushort* kn    = (ushort*)ws;      ws += (size_t)NROWS_ * D_ * 2;
    ushort* vn    = (ushort*)ws;      ws += (size_t)NROWS_ * D_ * 2;
    ushort* wqb   = (ushort*)ws;      ws += (size_t)D_ * D_ * 2;
    ushort* wkb   = (ushort*)ws;      ws += (size_t)D_ * D_ * 2;
    ushort* wvb   = (ushort*)ws;      ws += (size_t)D_ * D_ * 2;
    ushort* wfcb  = (ushort*)ws;      ws += (size_t)D_ * D_ * 2;
    ushort* qh    = (ushort*)ws;      ws += (size_t)NROWS_ * D_ * 2;
    ushort* kh    = (ushort*)ws;      ws += (size_t)NROWS_ * D_ * 2;
    ushort* vtw   = (ushort*)ws;      ws += (size_t)NROWS_ * D_ * 2;
    ushort* ctx   = qn;               // qn is dead after the first GEMM; reuse

    ln_norm_kernel<<<dim3(NROWS_, 3), 256, 0, stream>>>(q, k, v, ln1w, ln1b, ln2w, ln2b, ln3w, ln3b, qn, kn, vn);
    wcvt_kernel<<<dim3(1024, 4), 256, 0, stream>>>(wq, wk, wv, wfc, wqb, wkb, wvb, wfcb);
    maskbits_kernel<<<(B_*L_*L_)/256, 256, 0, stream>>>(mask, mbits);

    mm_kernel<0><<<dim3(32, 8), 256, 0, stream>>>(qn, wqb, qh);
    mm_kernel<0><<<dim3(32, 8), 256, 0, stream>>>(kn, wkb, kh);
    mm_kernel<1><<<dim3(8, 32), 256, 0, stream>>>(wvb, vn, vtw);   // C^T trick for [b][h][d][seq]

    attn_kernel<<<dim3(L_/64, H_, B_), 256, 0, stream>>>(qh, kh, vtw, mbits, attn_out, ctx);

    mm_kernel<2><<<dim3(32, 8), 256, 0, stream>>>(ctx, wfcb, dyn_out);
}

// Round 4
// 214.842 us; speedup vs baseline: 7.2234x; 1.0543x over previous
//
#include <hip/hip_runtime.h>
#include <hip/hip_bf16.h>

#define B_ 4
#define L_ 1024
#define D_ 1024
#define H_ 16
#define NROWS_ (B_ * L_)   // 4096

typedef __attribute__((ext_vector_type(8))) short short8;
typedef __attribute__((ext_vector_type(4))) float f32x4;

__device__ __forceinline__ ushort f2bf(float f) {   // RNE
    union { float f; uint u; } x; x.f = f;
    return (ushort)((x.u + 0x7fffu + ((x.u >> 16) & 1u)) >> 16);
}
__device__ __forceinline__ float bf2f(ushort u) {
    union { uint u; float f; } x; x.u = (uint)u << 16; return x.f;
}
__device__ __forceinline__ void gl_lds16(const void* g, void* l) {
    __builtin_amdgcn_global_load_lds(
        (const __attribute__((address_space(1))) uint*)(uintptr_t)g,
        (__attribute__((address_space(3))) uint*)(uintptr_t)l, 16, 0, 0);
}

#define EXP2C 0.1803368801111244f   // 0.125 * log2(e)

// ---------------- fused LayerNorm -> bf16 ----------------
__global__ __launch_bounds__(256) void ln_norm_kernel(
    const float* __restrict__ q, const float* __restrict__ k, const float* __restrict__ v,
    const float* __restrict__ ln1w, const float* __restrict__ ln1b,
    const float* __restrict__ ln2w, const float* __restrict__ ln2b,
    const float* __restrict__ ln3w, const float* __restrict__ ln3b,
    ushort* __restrict__ qn, ushort* __restrict__ kn, ushort* __restrict__ vn)
{
    const int row = blockIdx.x, which = blockIdx.y, t = threadIdx.x;
    const float *x, *lw, *lb; ushort* out;
    if (which == 0)      { x = q; lw = ln1w; lb = ln1b; out = qn; }
    else if (which == 1) { x = k; lw = ln2w; lb = ln2b; out = kn; }
    else                 { x = v; lw = ln3w; lb = ln3b; out = vn; }
    x += (size_t)row * D_; out += (size_t)row * D_;
    const float4 t4 = ((const float4*)x)[t];
    float s  = t4.x + t4.y + t4.z + t4.w;
    float s2 = t4.x*t4.x + t4.y*t4.y + t4.z*t4.z + t4.w*t4.w;
    #pragma unroll
    for (int off = 1; off < 64; off <<= 1) {
        s  += __shfl_xor(s,  off, 64);
        s2 += __shfl_xor(s2, off, 64);
    }
    __shared__ float red[8];
    __shared__ float mr[2];
    const int wid = t >> 6;
    if ((t & 63) == 0) { red[wid*2] = s; red[wid*2+1] = s2; }
    __syncthreads();
    if (t == 0) {
        s  = red[0] + red[2] + red[4] + red[6];
        s2 = red[1] + red[3] + red[5] + red[7];
        const float mean = s * (1.0f/(float)D_);
        const float var  = s2 * (1.0f/(float)D_) - mean*mean;
        mr[0] = mean; mr[1] = rsqrtf(var + 1e-5f);
    }
    __syncthreads();
    const float mean = mr[0], rstd = mr[1];
    const float4 w4 = ((const float4*)lw)[t];
    const float4 b4 = ((const float4*)lb)[t];
    ushort4 o;
    o.x = f2bf((t4.x - mean)*rstd*w4.x + b4.x);
    o.y = f2bf((t4.y - mean)*rstd*w4.y + b4.y);
    o.z = f2bf((t4.z - mean)*rstd*w4.z + b4.z);
    o.w = f2bf((t4.w - mean)*rstd*w4.w + b4.w);
    ((ushort4*)out)[t] = o;
}

// ---------------- weights fp32 -> bf16 ----------------
__global__ __launch_bounds__(256) void wcvt_kernel(
    const float* __restrict__ w0, const float* __restrict__ w1,
    const float* __restrict__ w2, const float* __restrict__ w3,
    ushort* __restrict__ o0, ushort* __restrict__ o1,
    ushort* __restrict__ o2, ushort* __restrict__ o3)
{
    const int which = blockIdx.y;
    const float* src = which == 0 ? w0 : which == 1 ? w1 : which == 2 ? w2 : w3;
    ushort* dst      = which == 0 ? o0 : which == 1 ? o1 : which == 2 ? o2 : o3;
    const size_t i = (size_t)blockIdx.x * 256 + threadIdx.x;
    const float4 f = ((const float4*)src)[i];
    ushort4 o; o.x = f2bf(f.x); o.y = f2bf(f.y); o.z = f2bf(f.z); o.w = f2bf(f.w);
    ((ushort4*)dst)[i] = o;
}

// ---------------- mask -> gathered bit words ----------------
// gbits[row][lc] (uint2, 64 bits): bit j = (mask[row][lc + 16*j] != 0)
__global__ __launch_bounds__(256) void gatherbits_kernel(
    const int* __restrict__ mask, uint2* __restrict__ gbits)
{
    const int t = threadIdx.x;
    const int row = blockIdx.x * 16 + (t >> 4);
    const int lc = t & 15;
    const int* src = mask + (size_t)row * 1024 + lc;
    uint lo = 0, hi = 0;
    #pragma unroll
    for (int j = 0; j < 32; j++) lo |= (src[16*j]      != 0 ? 1u : 0u) << j;
    #pragma unroll
    for (int j = 0; j < 32; j++) hi |= (src[16*(j+32)] != 0 ? 1u : 0u) << j;
    gbits[(size_t)row*16 + lc] = make_uint2(lo, hi);
}

// ---------------- fused 3-way projection GEMM (bf16 MFMA, 128x128, BK=64) ----------------
// z=0: qh = qn@wq^T [b][h][seq][64] ; z=1: kh = kn@wk^T same ; z=2: vt = (wv@vn^T) -> [b][h][d][seq]
__global__ __launch_bounds__(256) void proj_kernel(
    const ushort* __restrict__ qn, const ushort* __restrict__ kn, const ushort* __restrict__ vn,
    const ushort* __restrict__ wqb, const ushort* __restrict__ wkb, const ushort* __restrict__ wvb,
    ushort* __restrict__ qh, ushort* __restrict__ kh, ushort* __restrict__ vtw)
{
    __shared__ __align__(16) ushort As[128*64];
    __shared__ __align__(16) ushort Bs[128*64];
    const int gid = blockIdx.x;
    const int z = gid % 3, id = gid / 3;
    const ushort *A, *W; ushort* out;
    if (z == 0)      { A = qn;  W = wqb; out = qh;  }
    else if (z == 1) { A = kn;  W = wkb; out = kh;  }
    else             { A = wvb; W = vn;  out = vtw; }
    int bm, bn;
    if (z < 2) { bm = (id >> 3) * 128; bn = (id & 7)  * 128; }
    else       { bm = (id >> 5) * 128; bn = (id & 31) * 128; }

    const int t = threadIdx.x, w = t >> 6, lane = t & 63;
    const int lc = lane & 15, g = lane >> 4;
    const int wr = w >> 1, wc = w & 1;
    const int srow = lane >> 3, sp = lane & 7;
    f32x4 acc[4][4] = {};

    for (int k0 = 0; k0 < 1024; k0 += 64) {
        #pragma unroll
        for (int j = 0; j < 4; j++) {
            const int i = w*4 + j;
            const int row = i*8 + srow;
            const int c = (sp - (row & 7)) & 7;
            gl_lds16(A + (size_t)(bm+row)*1024 + k0 + c*8, &As[i*512]);
            gl_lds16(W + (size_t)(bn+row)*1024 + k0 + c*8, &Bs[i*512]);
        }
        __syncthreads();
        #pragma unroll
        for (int ks = 0; ks < 2; ks++) {
            short8 af[4], bf4[4];
            #pragma unroll
            for (int mi = 0; mi < 4; mi++) {
                const int row = wr*64 + mi*16 + lc;
                af[mi] = *(const short8*)&As[row*64 + (((ks*4+g) + (row&7)) & 7)*8];
            }
            #pragma unroll
            for (int ni = 0; ni < 4; ni++) {
                const int row = wc*64 + ni*16 + lc;
                bf4[ni] = *(const short8*)&Bs[row*64 + (((ks*4+g) + (row&7)) & 7)*8];
            }
            #pragma unroll
            for (int mi = 0; mi < 4; mi++)
                #pragma unroll
                for (int ni = 0; ni < 4; ni++)
                    acc[mi][ni] = __builtin_amdgcn_mfma_f32_16x16x32_bf16(af[mi], bf4[ni], acc[mi][ni], 0, 0, 0);
        }
        __syncthreads();
    }

    #pragma unroll
    for (int mi = 0; mi < 4; mi++)
        #pragma unroll
        for (int ni = 0; ni < 4; ni++)
            #pragma unroll
            for (int r = 0; r < 4; r++) {
                const int m = bm + wr*64 + mi*16 + g*4 + r;
                const int n = bn + wc*64 + ni*16 + lc;
                const ushort val = f2bf(acc[mi][ni][r]);
                if (z < 2) {
                    const int bb = m >> 10, seq = m & 1023, hh = n >> 6, d = n & 63;
                    out[(((size_t)(bb*16+hh))*1024 + seq)*64 + d] = val;
                } else {
                    const int bb = n >> 10, seq = n & 1023, hh = m >> 6, d = m & 63;
                    out[((size_t)(bb*16+hh))*65536 + (size_t)d*1024 + seq] = val;
                }
            }
}

// ---------------- fc GEMM: 128x64 tile (512 blocks -> 2/CU), fp32 out ----------------
__global__ __launch_bounds__(256) void fc_kernel(
    const ushort* __restrict__ A, const ushort* __restrict__ W, float* __restrict__ C)
{
    __shared__ __align__(16) ushort As[128*64];
    __shared__ __align__(16) ushort Bs[64*64];
    const int t = threadIdx.x, w = t >> 6, lane = t & 63;
    const int lc = lane & 15, g = lane >> 4;
    const int wr = w >> 1, wc = w & 1;
    const int bm = blockIdx.x * 128, bn = blockIdx.y * 64;
    const int srow = lane >> 3, sp = lane & 7;
    f32x4 acc[4][2] = {};

    for (int k0 = 0; k0 < 1024; k0 += 64) {
        #pragma unroll
        for (int j = 0; j < 4; j++) {
            const int i = w*4 + j;
            const int row = i*8 + srow;
            const int c = (sp - (row & 7)) & 7;
            gl_lds16(A + (size_t)(bm+row)*1024 + k0 + c*8, &As[i*512]);
        }
        #pragma unroll
        for (int j = 0; j < 2; j++) {
            const int i = w*2 + j;
            const int row = i*8 + srow;
            const int c = (sp - (row & 7)) & 7;
            gl_lds16(W + (size_t)(bn+row)*1024 + k0 + c*8, &Bs[i*512]);
        }
        __syncthreads();
        #pragma unroll
        for (int ks = 0; ks < 2; ks++) {
            short8 af[4], bf4[2];
            #pragma unroll
            for (int mi = 0; mi < 4; mi++) {
                const int row = wr*64 + mi*16 + lc;
                af[mi] = *(const short8*)&As[row*64 + (((ks*4+g) + (row&7)) & 7)*8];
            }
            #pragma unroll
            for (int ni = 0; ni < 2; ni++) {
                const int row = wc*32 + ni*16 + lc;
                bf4[ni] = *(const short8*)&Bs[row*64 + (((ks*4+g) + (row&7)) & 7)*8];
            }
            #pragma unroll
            for (int mi = 0; mi < 4; mi++)
                #pragma unroll
                for (int ni = 0; ni < 2; ni++)
                    acc[mi][ni] = __builtin_amdgcn_mfma_f32_16x16x32_bf16(af[mi], bf4[ni], acc[mi][ni], 0, 0, 0);
        }
        __syncthreads();
    }

    #pragma unroll
    for (int mi = 0; mi < 4; mi++)
        #pragma unroll
        for (int ni = 0; ni < 2; ni++)
            #pragma unroll
            for (int r = 0; r < 4; r++)
                C[(size_t)(bm + wr*64 + mi*16 + g*4 + r)*1024 + bn + wc*32 + ni*16 + lc] = acc[mi][ni][r];
}

// ---------------- MFMA attention: fixed-max softmax, dbuf K/V, coalesced p-write ----------------
__global__ __launch_bounds__(256) void attn_kernel(
    const ushort* __restrict__ qh, const ushort* __restrict__ kh, const ushort* __restrict__ vt,
    const uint2* __restrict__ gbits, float* __restrict__ p_out, ushort* __restrict__ ctx)
{
    __shared__ __align__(16) ushort Qs[64*72];
    __shared__ __align__(16) ushort Ks[2][64*64];
    __shared__ __align__(16) ushort Vs[2][64*64];
    __shared__ __align__(16) ushort Pb[4][16*72];
    __shared__ float invs[4][16];
    const int t = threadIdx.x, w = t >> 6, lane = t & 63;
    const int lc = lane & 15, g = lane >> 4;
    const int q0 = blockIdx.x * 64, h = blockIdx.y, b = blockIdx.z;
    const ushort* qbase = qh + ((size_t)(b*16+h)*1024 + q0)*64;
    const ushort* kbase = kh + (size_t)(b*16+h)*1024*64;
    const ushort* vbase = vt + (size_t)(b*16+h)*64*1024;
    const int srow = lane >> 3, sp = lane & 7;
    const int qrow = w * 16;

    {   // stage Q (padded 72)
        const int row = t >> 2, seg = (t & 3) * 16;
        *(short8*)&Qs[row*72+seg+0] = *(const short8*)(qbase + (size_t)row*64 + seg + 0);
        *(short8*)&Qs[row*72+seg+8] = *(const short8*)(qbase + (size_t)row*64 + seg + 8);
    }
    // gathered mask bits: 4 rows per thread, 64 bits each
    unsigned long long gb[4];
    #pragma unroll
    for (int r = 0; r < 4; r++) {
        const uint2 u = gbits[((size_t)(b*1024 + q0 + qrow + g*4 + r))*16 + lc];
        gb[r] = ((unsigned long long)u.y << 32) | (unsigned long long)u.x;
    }
    // prefetch K tile 0 into buf 0
    #pragma unroll
    for (int j = 0; j < 2; j++) {
        const int i = w*2 + j, row = i*8 + srow, c = (sp - (row & 7)) & 7;
        gl_lds16(kbase + ((size_t)row)*64 + c*8, &Ks[0][i*512]);
    }
    __syncthreads();

    const short8 aq0 = *(const short8*)&Qs[(qrow+lc)*72 + g*8];
    const short8 aq1 = *(const short8*)&Qs[(qrow+lc)*72 + 32 + g*8];

    float s_part[4] = {0.f, 0.f, 0.f, 0.f};

    // ---- pass 1: row sums of masked exp(s/8), K double-buffered ----
    for (int kt = 0; kt < 16; kt++) {
        const int cur = kt & 1;
        if (kt < 15) {
            #pragma unroll
            for (int j = 0; j < 2; j++) {
                const int i = w*2 + j, row = i*8 + srow, c = (sp - (row & 7)) & 7;
                gl_lds16(kbase + ((size_t)((kt+1)*64+row))*64 + c*8, &Ks[cur^1][i*512]);
            }
        }
        f32x4 sacc[4];
        #pragma unroll
        for (int ni = 0; ni < 4; ni++) {
            const int row = ni*16 + lc;
            const short8 b0 = *(const short8*)&Ks[cur][row*64 + (((g  ) + (row&7)) & 7)*8];
            const short8 b1 = *(const short8*)&Ks[cur][row*64 + (((4+g) + (row&7)) & 7)*8];
            f32x4 z = {0.f,0.f,0.f,0.f};
            z = __builtin_amdgcn_mfma_f32_16x16x32_bf16(aq0, b0, z, 0, 0, 0);
            z = __builtin_amdgcn_mfma_f32_16x16x32_bf16(aq1, b1, z, 0, 0, 0);
            sacc[ni] = z;
        }
        #pragma unroll
        for (int r = 0; r < 4; r++) {
            #pragma unroll
            for (int ni = 0; ni < 4; ni++) {
                const bool mk = (gb[r] >> (kt*4 + ni)) & 1ull;
                s_part[r] += mk ? 0.f : exp2f(sacc[ni][r] * EXP2C);
            }
        }
        __syncthreads();
    }

    // prefetch pass-2 tile 0 while reducing
    #pragma unroll
    for (int j = 0; j < 2; j++) {
        const int i = w*2 + j, row = i*8 + srow, c = (sp - (row & 7)) & 7;
        gl_lds16(kbase + ((size_t)row)*64 + c*8, &Ks[0][i*512]);
        gl_lds16(vbase + (size_t)row*1024 + c*8, &Vs[0][i*512]);
    }
    float inv[4];
    #pragma unroll
    for (int r = 0; r < 4; r++) {
        float s = s_part[r];
        #pragma unroll
        for (int off = 1; off < 16; off <<= 1) s += __shfl_xor(s, off, 64);
        inv[r] = (s > 0.f) ? (1.0f / s) : 0.f;
        if (lc == 0) invs[w][g*4 + r] = inv[r];
    }
    __syncthreads();

    // ---- pass 2: recompute, PV on unnormalized e, coalesced p-write ----
    f32x4 cacc[4] = {{0,0,0,0},{0,0,0,0},{0,0,0,0},{0,0,0,0}};
    float* pblk = p_out + ((size_t)(h*B_ + b)*1024 + q0)*1024;
    for (int kt = 0; kt < 16; kt++) {
        const int cur = kt & 1;
        if (kt < 15) {
            #pragma unroll
            for (int j = 0; j < 2; j++) {
                const int i = w*2 + j, row = i*8 + srow, c = (sp - (row & 7)) & 7;
                gl_lds16(kbase + ((size_t)((kt+1)*64+row))*64 + c*8, &Ks[cur^1][i*512]);
                gl_lds16(vbase + (size_t)row*1024 + (kt+1)*64 + c*8, &Vs[cur^1][i*512]);
            }
        }
        f32x4 sacc[4];
        #pragma unroll
        for (int ni = 0; ni < 4; ni++) {
            const int row = ni*16 + lc;
            const short8 b0 = *(const short8*)&Ks[cur][row*64 + (((g  ) + (row&7)) & 7)*8];
            const short8 b1 = *(const short8*)&Ks[cur][row*64 + (((4+g) + (row&7)) & 7)*8];
            f32x4 z = {0.f,0.f,0.f,0.f};
            z = __builtin_amdgcn_mfma_f32_16x16x32_bf16(aq0, b0, z, 0, 0, 0);
            z = __builtin_amdgcn_mfma_f32_16x16x32_bf16(aq1, b1, z, 0, 0, 0);
            sacc[ni] = z;
        }
        #pragma unroll
        for (int r = 0; r < 4; r++)
            #pragma unroll
            for (int ni = 0; ni < 4; ni++) {
                const bool mk = (gb[r] >> (kt*4 + ni)) & 1ull;
                const float e = mk ? 0.f : exp2f(sacc[ni][r] * EXP2C);
                Pb[w][(g*4+r)*72 + ni*16 + lc] = f2bf(e);
            }
        const short8 pa0 = *(const short8*)&Pb[w][lc*72 + g*8];
        const short8 pa1 = *(const short8*)&Pb[w][lc*72 + 32 + g*8];
        #pragma unroll
        for (int di = 0; di < 4; di++) {
            const int row = di*16 + lc;
            const short8 vb0 = *(const short8*)&Vs[cur][row*64 + (((g  ) + (row&7)) & 7)*8];
            const short8 vb1 = *(const short8*)&Vs[cur][row*64 + (((4+g) + (row&7)) & 7)*8];
            cacc[di] = __builtin_amdgcn_mfma_f32_16x16x32_bf16(pa0, vb0, cacc[di], 0, 0, 0);
            cacc[di] = __builtin_amdgcn_mfma_f32_16x16x32_bf16(pa1, vb1, cacc[di], 0, 0, 0);
        }
        {   // coalesced p write: wave covers its 16 rows x 64 cols from Pb
            const int rr = lane >> 2, c4 = (lane & 3) * 16;
            const float iv = invs[w][rr];
            const short8 e0 = *(const short8*)&Pb[w][rr*72 + c4 + 0];
            const short8 e1 = *(const short8*)&Pb[w][rr*72 + c4 + 8];
            float* dst = pblk + (size_t)(qrow+rr)*1024 + kt*64 + c4;
            float4 o;
            o.x = bf2f((ushort)e0[0])*iv; o.y = bf2f((ushort)e0[1])*iv;
            o.z = bf2f((ushort)e0[2])*iv; o.w = bf2f((ushort)e0[3])*iv;
            *(float4*)(dst + 0) = o;
            o.x = bf2f((ushort)e0[4])*iv; o.y = bf2f((ushort)e0[5])*iv;
            o.z = bf2f((ushort)e0[6])*iv; o.w = bf2f((ushort)e0[7])*iv;
            *(float4*)(dst + 4) = o;
            o.x = bf2f((ushort)e1[0])*iv; o.y = bf2f((ushort)e1[1])*iv;
            o.z = bf2f((ushort)e1[2])*iv; o.w = bf2f((ushort)e1[3])*iv;
            *(float4*)(dst + 8) = o;
            o.x = bf2f((ushort)e1[4])*iv; o.y = bf2f((ushort)e1[5])*iv;
            o.z = bf2f((ushort)e1[6])*iv; o.w = bf2f((ushort)e1[7])*iv;
            *(float4*)(dst + 12) = o;
        }
        __syncthreads();
    }

    // ---- ctx epilogue: transpose through Pb for contiguous 128B row stores ----
    #pragma unroll
    for (int di = 0; di < 4; di++)
        #pragma unroll
        for (int r = 0; r < 4; r++)
            Pb[w][(g*4+r)*72 + di*16 + lc] = f2bf(cacc[di][r] * inv[r]);
    {
        const int rr = lane >> 2, seg = (lane & 3) * 16;
        const short8 c0 = *(const short8*)&Pb[w][rr*72 + seg + 0];
        const short8 c1 = *(const short8*)&Pb[w][rr*72 + seg + 8];
        ushort* dst = ctx + ((size_t)(b*1024 + q0 + qrow + rr))*1024 + h*64 + seg;
        *(short8*)(dst + 0) = c0;
        *(short8*)(dst + 8) = c1;
    }
}

extern "C" void kernel_launch(void* const* d_in, const int* in_sizes, int n_in,
                              void* d_out, int out_size, void* d_ws, size_t ws_size,
                              hipStream_t stream)
{
    const float* q    = (const float*)d_in[0];
    const float* k    = (const float*)d_in[1];
    const float* v    = (const float*)d_in[2];
    const int*   mask = (const int*)d_in[4];
    const float* ln1w = (const float*)d_in[5];
    const float* ln1b = (const float*)d_in[6];
    const float* ln2w = (const float*)d_in[7];
    const float* ln2b = (const float*)d_in[8];
    const float* ln3w = (const float*)d_in[9];
    const float* ln3b = (const float*)d_in[10];
    const float* wq   = (const float*)d_in[11];
    const float* wk   = (const float*)d_in[12];
    const float* wv   = (const float*)d_in[13];
    const float* wfc  = (const float*)d_in[14];

    float* dyn_out  = (float*)d_out;                       // [B, L, D]
    float* attn_out = dyn_out + (size_t)B_ * L_ * D_;      // [H*B, L, L]

    char* ws = (char*)d_ws;
    uint2*  gbits = (uint2*)ws;       ws += (size_t)NROWS_ * 16 * 8;         // 512 KB
    ushort* qn    = (ushort*)ws;      ws += (size_t)NROWS_ * D_ * 2;
    ushort* kn    = (ushort*)ws;      ws += (size_t)NROWS_ * D_ * 2;
    ushort* vn    = (ushort*)ws;      ws += (size_t)NROWS_ * D_ * 2;
    ushort* wqb   = (ushort*)ws;      ws += (size_t)D_ * D_ * 2;
    ushort* wkb   = (ushort*)ws;      ws += (size_t)D_ * D_ * 2;
    ushort* wvb   = (ushort*)ws;      ws += (size_t)D_ * D_ * 2;
    ushort* wfcb  = (ushort*)ws;      ws += (size_t)D_ * D_ * 2;
    ushort* qh    = (ushort*)ws;      ws += (size_t)NROWS_ * D_ * 2;
    ushort* kh    = (ushort*)ws;      ws += (size_t)NROWS_ * D_ * 2;
    ushort* vtw   = (ushort*)ws;      ws += (size_t)NROWS_ * D_ * 2;
    ushort* ctx   = qn;               // qn dead after proj; reuse

    ln_norm_kernel<<<dim3(NROWS_, 3), 256, 0, stream>>>(q, k, v, ln1w, ln1b, ln2w, ln2b, ln3w, ln3b, qn, kn, vn);
    wcvt_kernel<<<dim3(1024, 4), 256, 0, stream>>>(wq, wk, wv, wfc, wqb, wkb, wvb, wfcb);
    gatherbits_kernel<<<NROWS_/16, 256, 0, stream>>>(mask, gbits);

    proj_kernel<<<768, 256, 0, stream>>>(qn, kn, vn, wqb, wkb, wvb, qh, kh, vtw);

    attn_kernel<<<dim3(L_/64, H_, B_), 256, 0, stream>>>(qh, kh, vtw, gbits, attn_out, ctx);

    fc_kernel<<<dim3(32, 16), 256, 0, stream>>>(ctx, wfcb, dyn_out);
}